// Round 9
// baseline (155.956 us; speedup 1.0000x reference)
//
#include <hip/hip_runtime.h>
#include <hip/hip_bf16.h>

#define NPAIR 136
#define NH 68          // pairs per half (136 = 2*68)
#define NOUT 17408     // NH * 256 threads
#define GENE_BLK 512   // 32 clouds per block, 8 per wave
#define CELL_BLK 512
#define NCHUNK 8       // reduce1 chunks (CELL_BLK/64)

using frag8 = __attribute__((ext_vector_type(8))) short;
using f32x4 = __attribute__((ext_vector_type(4))) float;
using i32x4 = __attribute__((ext_vector_type(4))) int;

// Pack two f32 -> bf16x2 by truncation with ONE v_perm_b32.
__device__ inline int pack_bf16(float lo, float hi){
  unsigned a, b;
  __builtin_memcpy(&a, &hi, 4);
  __builtin_memcpy(&b, &lo, 4);
  return (int)__builtin_amdgcn_perm(a, b, 0x07060302u);
}

__device__ inline float bf2f(unsigned short v){
  unsigned u32 = ((unsigned)v) << 16;
  float f; __builtin_memcpy(&f, &u32, 4);
  return f;
}

struct PairTab { int pi[NPAIR]; int pj[NPAIR]; };
constexpr PairTab make_pairs(){
  PairTab t{}; int u = 0;
  for (int i = 0; i < 16; ++i) for (int j = i; j < 16; ++j){ t.pi[u]=i; t.pj[u]=j; ++u; }
  return t;
}
constexpr PairTab PT = make_pairs();

// ---------------- gene: contiguous streaming via global_load_lds ----------------
__device__ inline void gload16(const void* src, void* dst){
  __builtin_amdgcn_global_load_lds(
      (const __attribute__((address_space(1))) unsigned int*)src,
      (__attribute__((address_space(3))) unsigned int*)dst, 16, 0, 0);
}

// Stage quarter q (128 floats/row) of cloud b into an 8KB wave-private buffer.
// LDS layout: row r at [r*512, r*512+512), column bytes XOR-swizzled by ((r&3)<<4).
// Each of the 8 instructions covers 2 rows, per-lane CONTIGUOUS (permuted within
// 128-B windows only -> same coalesced requests). hl = lane>>5.
__device__ inline void stage_quarter(const char* Xc, const char* Yc, int b, int q,
                                     char* buf, int cpe, int cpo, int hl){
#pragma unroll
  for (int i = 0; i < 8; ++i){
    const char* base = (i < 4) ? Xc : Yc;          // rows 0-7 = X, 8-15 = Y
    int cp = (i & 1) ? cpo : cpe;                  // swizzle variant (r&3 parity)
    const char* src = base + (size_t)b*16384
                    + (size_t)((2*(i & 3) + hl)*2048 + q*512 + cp);
    gload16(src, buf + i*1024);
  }
}

// 4 MFMA K-steps from one staged quarter. A0/A16 are per-lane swizzled bases.
__device__ inline void quarter_mfma(const char* buf, int A0, int A16, f32x4& acc){
#pragma unroll
  for (int kk = 0; kk < 4; ++kk){
    f32x4 w0 = *reinterpret_cast<const f32x4*>(buf + A0  + kk*128);
    f32x4 w1 = *reinterpret_cast<const f32x4*>(buf + A16 + kk*128);
    i32x4 fi;
    fi[0] = pack_bf16(w0[0], w0[1]); fi[1] = pack_bf16(w0[2], w0[3]);
    fi[2] = pack_bf16(w1[0], w1[1]); fi[3] = pack_bf16(w1[2], w1[3]);
    frag8 fr = __builtin_bit_cast(frag8, fi);
    acc = __builtin_amdgcn_mfma_f32_16x16x32_bf16(fr, fr, acc, 0, 0, 0);
  }
}

// One wave per cloud stream; zero barriers; wave-private double-buffered quarters.
__global__ __launch_bounds__(256) void gene_kernel(const float* __restrict__ X,
                                                   const float* __restrict__ Y,
                                                   float* __restrict__ gene_part){
  __shared__ char lds[65536];          // 4 waves x (2 x 8KB quarter buffers)
  const int t = threadIdx.x, wave = t >> 6, lane = t & 63;
  char* buf0 = lds + wave*16384;
  char* buf1 = buf0 + 8192;
  const int r = lane & 15, g = lane >> 4;
  const int swz = (r & 3) << 4;
  const int A0  = r*512 + ((g*32) ^ swz);
  const int A16 = r*512 + ((g*32 + 16) ^ swz);
  const int hl = lane >> 5;
  const int c16 = (lane & 31)*16;
  const int cpe = c16 ^ (hl << 4);           // source pre-swizzle, even rows (r&3 = hl)
  const int cpo = c16 ^ ((2 + hl) << 4);     // odd i rows (r&3 = 2+hl)
  const char* Xc = (const char*)X;
  const char* Yc = (const char*)Y;
  const int b0 = blockIdx.x*32 + wave*8;     // this wave's 8 clouds
  float gene_acc = 0.f;

  stage_quarter(Xc, Yc, b0, 0, buf0, cpe, cpo, hl);   // quarter j=0
  stage_quarter(Xc, Yc, b0, 1, buf1, cpe, cpo, hl);   // quarter j=1
  f32x4 acc0 = {0.f,0.f,0.f,0.f}, acc1 = {0.f,0.f,0.f,0.f};
  for (int s = 0; s < 16; ++s){              // 32 quarters = 8 clouds
    const int j0 = 2*s;
    if ((s & 1) == 0){
      acc0 = f32x4{0.f,0.f,0.f,0.f};
      acc1 = f32x4{0.f,0.f,0.f,0.f};
    }
    quarter_mfma(buf0, A0, A16, acc0);       // compute j0
    if (j0 + 2 < 32)
      stage_quarter(Xc, Yc, b0 + ((j0+2) >> 2), (j0+2) & 3, buf0, cpe, cpo, hl);
    quarter_mfma(buf1, A0, A16, acc1);       // compute j0+1
    if (j0 + 3 < 32)
      stage_quarter(Xc, Yc, b0 + ((j0+3) >> 2), (j0+3) & 3, buf1, cpe, cpo, hl);
    if (s & 1){                              // cloud finished (4 quarters)
      f32x4 acc = acc0 + acc1;
      // diag exchange via bpermute (r8-verified): diag[d] in lane d+16*(d>>2)
      float mydiag = acc[0];
      mydiag = ((r & 3) == 1) ? acc[1] : mydiag;
      mydiag = ((r & 3) == 2) ? acc[2] : mydiag;
      mydiag = ((r & 3) == 3) ? acc[3] : mydiag;
      int md = __builtin_bit_cast(int, mydiag);
      float dcol = __builtin_bit_cast(float,
          __builtin_amdgcn_ds_bpermute(4*(r + 16*(r >> 2)), md));
      float sc = 0.f;
#pragma unroll
      for (int qq = 0; qq < 4; ++qq){
        float drow = __builtin_bit_cast(float,
            __builtin_amdgcn_ds_bpermute(4*(20*g + qq), md));
        int row = g*4 + qq;
        float sqd = drow + dcol - 2.f*acc[qq];
        float dist = sqrtf(fmaxf(sqd, 0.f));
        sc += (((row < 8) == (r < 8)) ? -dist : dist);
      }
      gene_acc += sc;
    }
  }
#pragma unroll
  for (int off = 32; off > 0; off >>= 1) gene_acc += __shfl_xor(gene_acc, off);
  if (lane == 0) gene_part[blockIdx.x*4 + wave] = gene_acc * (1.f/128.f);
}

// ---------------- cell: separate fp32 gather kernel (r1 structure) ----------------
template<int H>
__device__ inline void cell_body(const float* __restrict__ X, const float* __restrict__ Y,
                                 unsigned short* __restrict__ partials, int f, int t, int p){
  float acc[NH];
#pragma unroll
  for (int u = 0; u < NH; ++u) acc[u] = 0.f;
  for (int b = p; b < 16384; b += CELL_BLK){
    const float* xb = X + (size_t)b*4096 + 384 + f;
    const float* yb = Y + (size_t)b*4096 + 384 + f;
    float z[16];
#pragma unroll
    for (int i = 0; i < 8; ++i) z[i]   = xb[(size_t)i*512];
#pragma unroll
    for (int i = 0; i < 8; ++i) z[8+i] = yb[(size_t)i*512];
#pragma unroll
    for (int u = 0; u < NH; ++u)
      acc[u] = fmaf(z[PT.pi[H*NH+u]], z[PT.pj[H*NH+u]], acc[u]);
  }
  unsigned short* dst = partials + (size_t)p*NOUT;
#pragma unroll
  for (int u = 0; u < NH; ++u){
    __hip_bfloat16 bv = __float2bfloat16(acc[u]);
    unsigned short sv; __builtin_memcpy(&sv, &bv, 2);
    dst[u*256 + t] = sv;
  }
}

__global__ __launch_bounds__(256) void cell_kernel(const float* __restrict__ X,
                                                   const float* __restrict__ Y,
                                                   unsigned short* __restrict__ partials){
  const int t = threadIdx.x;
  const int f = t & 127;
  const int h = t >> 7;                // wave-uniform
  if (h == 0) cell_body<0>(X, Y, partials, f, t, blockIdx.x);
  else        cell_body<1>(X, Y, partials, f, t, blockIdx.x);
}

__global__ __launch_bounds__(256) void reduce1_kernel(const unsigned short* __restrict__ partials,
                                                      float* __restrict__ partial2){
  int o = (blockIdx.x % 68)*256 + threadIdx.x;   // 68*256 = NOUT exactly
  int c = blockIdx.x / 68;                       // NCHUNK chunks of 64 blocks
  int p0 = c*64, p1 = p0 + 64;
  float s0=0.f, s1=0.f, s2=0.f, s3=0.f;
  for (int p = p0; p < p1; p += 4){
    s0 += bf2f(partials[(size_t)(p+0)*NOUT + o]);
    s1 += bf2f(partials[(size_t)(p+1)*NOUT + o]);
    s2 += bf2f(partials[(size_t)(p+2)*NOUT + o]);
    s3 += bf2f(partials[(size_t)(p+3)*NOUT + o]);
  }
  partial2[(size_t)c*NOUT + o] = (s0+s1)+(s2+s3);
}

__global__ __launch_bounds__(256) void reduce2_kernel(const float* __restrict__ partial2,
                                                      float* __restrict__ G){
  int o = blockIdx.x*256 + threadIdx.x;          // grid 68
  float s = 0.f;
#pragma unroll
  for (int c = 0; c < NCHUNK; ++c) s += partial2[(size_t)c*NOUT + o];
  G[o] = s;
}

__device__ inline float getG(const float* __restrict__ G, int f, int i, int j){
  int a = i < j ? i : j, c = i < j ? j : i;
  int k = a*16 - (a*(a-1))/2 + (c - a);          // linear index of (a,c), a<=c
  int hh = (k >= NH) ? 1 : 0;
  int u = k - hh*NH;
  return G[u*256 + hh*128 + f];
}

__global__ __launch_bounds__(256) void final_kernel(const float* __restrict__ G,
                                                    const float* __restrict__ gene_part,
                                                    int ngp, float* __restrict__ out){
  int t = threadIdx.x;
  float v = 0.f;
  if (t < 128){
    int f = t;
    float d[16];
#pragma unroll
    for (int i = 0; i < 16; ++i) d[i] = getG(G, f, i, i);
    float sum = 0.f;
#pragma unroll
    for (int i = 0; i < 16; ++i){
#pragma unroll
      for (int j = 0; j < 16; ++j){
        float sqd = d[i] + d[j] - 2.f*getG(G, f, i, j);
        float dist = sqrtf(fmaxf(sqd, 0.f));
        sum += (((i < 8) == (j < 8)) ? -dist : dist);
      }
    }
    v = sum * (1.f/128.f) * (1.f/128.f);         // per-feature value / 128 features
  }
  float gp = 0.f;
  for (int idx = t; idx < ngp; idx += 256) gp += gene_part[idx];
  v += gp * (1.f/16384.f);                       // mean over clouds
  __shared__ float red[256];
  red[t] = v;
  __syncthreads();
  for (int s2 = 128; s2 > 0; s2 >>= 1){
    if (t < s2) red[t] += red[t + s2];
    __syncthreads();
  }
  if (t == 0) out[0] = red[0];
}

extern "C" void kernel_launch(void* const* d_in, const int* in_sizes, int n_in,
                              void* d_out, int out_size, void* d_ws, size_t ws_size,
                              hipStream_t stream){
  const float* X = (const float*)d_in[0];
  const float* Y = (const float*)d_in[1];
  float* out = (float*)d_out;

  float* wsf       = (float*)d_ws;
  float* gene_part = wsf;                            // GENE_BLK*4 = 2048 floats
  float* Gbuf      = wsf + 2048;                     // NOUT floats
  float* partial2  = wsf + 2048 + NOUT;              // NCHUNK*NOUT floats
  unsigned short* partials =
      (unsigned short*)(wsf + 2048 + (1+NCHUNK)*NOUT);  // CELL_BLK*NOUT bf16 (~17.8 MB)

  gene_kernel<<<GENE_BLK, 256, 0, stream>>>(X, Y, gene_part);
  cell_kernel<<<CELL_BLK, 256, 0, stream>>>(X, Y, partials);
  reduce1_kernel<<<68*NCHUNK, 256, 0, stream>>>(partials, partial2);
  reduce2_kernel<<<68, 256, 0, stream>>>(partial2, Gbuf);
  final_kernel<<<1, 256, 0, stream>>>(Gbuf, gene_part, 2048, out);
}

// Round 10
// 132.950 us; speedup vs baseline: 1.1730x; 1.1730x over previous
//
#include <hip/hip_runtime.h>
#include <hip/hip_bf16.h>

#define NPAIR 136
#define NH 68          // pairs per half (136 = 2*68)
#define NOUT 17408     // NH * 256 threads
#define NBLK 512       // fused grid: 32 clouds/block, 2 blocks/CU
#define NCHUNK 8       // reduce1 chunks (NBLK/64)

using frag8 = __attribute__((ext_vector_type(8))) short;
using f32x4 = __attribute__((ext_vector_type(4))) float;
using i32x4 = __attribute__((ext_vector_type(4))) int;

// Pack two f32 -> bf16x2 by truncation with ONE v_perm_b32.
__device__ inline int pack_bf16(float lo, float hi){
  unsigned a, b;
  __builtin_memcpy(&a, &hi, 4);
  __builtin_memcpy(&b, &lo, 4);
  return (int)__builtin_amdgcn_perm(a, b, 0x07060302u);
}

__device__ inline float bf2f(unsigned short v){
  unsigned u32 = ((unsigned)v) << 16;
  float f; __builtin_memcpy(&f, &u32, 4);
  return f;
}

struct PairTab { int pi[NPAIR]; int pj[NPAIR]; };
constexpr PairTab make_pairs(){
  PairTab t{}; int u = 0;
  for (int i = 0; i < 16; ++i) for (int j = i; j < 16; ++j){ t.pi[u]=i; t.pj[u]=j; ++u; }
  return t;
}
constexpr PairTab PT = make_pairs();

// Consumer: accumulate 68 pair-products for feature f over 8 clouds in cb.
// cb layout: [cloud 0..7][row 0..15][f 0..127] bf16, byte ^= ((row&7)<<4) swizzle.
template<int H>
__device__ inline void cell_accum(const char* cb, int f, float (&cacc)[NH]){
#pragma unroll
  for (int c = 0; c < 8; ++c){
    float z[16];
#pragma unroll
    for (int rr = 0; rr < 16; ++rr){
      int byte = ((c*16 + rr)*256 + f*2) ^ ((rr & 7) << 4);
      unsigned short v = *reinterpret_cast<const unsigned short*>(cb + byte);
      z[rr] = bf2f(v);
    }
#pragma unroll
    for (int u = 0; u < NH; ++u)      // compile-time pair indices -> all regs
      cacc[u] = fmaf(z[PT.pi[H*NH+u]], z[PT.pj[H*NH+u]], cacc[u]);
  }
}

// ---- fused: gene Gram via MFMA + cell Gram from the same loaded data ----
// Champion r6 body; 8 clouds/pass (2 per wave), bpermute diag (no LDS diag),
// one barrier per pass. No 2nd __launch_bounds__ arg (it clamps occupancy).
__global__ __launch_bounds__(256) void fused_kernel(const float* __restrict__ X,
                                                    const float* __restrict__ Y,
                                                    unsigned short* __restrict__ cell_partials,
                                                    float* __restrict__ gene_part){
  __shared__ char cellbuf[65536];      // 2 x (8 clouds x 16 rows x 128 f bf16)
  const int t = threadIdx.x;
  const int wave = t >> 6, lane = t & 63;
  const int r = lane & 15;             // row of Z (0-7 = X, 8-15 = Y)
  const int g = lane >> 4;             // k-group
  const int f = t & 127;               // cell feature
  const int h = t >> 7;                // pair-half 0/1 (wave-uniform)

  float cacc[NH];
#pragma unroll
  for (int u = 0; u < NH; ++u) cacc[u] = 0.f;
  float gene_acc = 0.f;

  const int cbase = blockIdx.x * 32;   // 32 clouds per block: 4 passes x 8 clouds
  for (int pass = 0; pass < 4; ++pass){
    char* cb = cellbuf + (pass & 1)*32768;
#pragma unroll
    for (int sub = 0; sub < 2; ++sub){
      const int ci = sub*4 + wave;                  // cloud slot 0..7 in this pass
      const int b = cbase + pass*8 + ci;
      const float* base = (r < 8) ? X + (size_t)b*4096 + (size_t)r*512
                                  : Y + (size_t)b*4096 + (size_t)(r-8)*512;
      const float* p = base + g*8;
      f32x4 acc0 = {0.f,0.f,0.f,0.f}, acc1 = {0.f,0.f,0.f,0.f};
#pragma unroll
      for (int kk = 0; kk < 16; ++kk){
        const float4* q4 = reinterpret_cast<const float4*>(p + kk*32);
        float4 v0 = q4[0];
        float4 v1 = q4[1];
        i32x4 fi;
        fi[0] = pack_bf16(v0.x, v0.y);
        fi[1] = pack_bf16(v0.z, v0.w);
        fi[2] = pack_bf16(v1.x, v1.y);
        fi[3] = pack_bf16(v1.z, v1.w);
        if (kk >= 12){                 // columns 384..511 -> stage for cell
          int byte = ((ci*16 + r)*256 + (kk-12)*64 + g*16) ^ ((r & 7) << 4);
          *reinterpret_cast<i32x4*>(cb + byte) = fi;
        }
        frag8 fr = __builtin_bit_cast(frag8, fi);
        if (kk & 1) acc1 = __builtin_amdgcn_mfma_f32_16x16x32_bf16(fr, fr, acc1, 0, 0, 0);
        else        acc0 = __builtin_amdgcn_mfma_f32_16x16x32_bf16(fr, fr, acc0, 0, 0, 0);
      }
      f32x4 acc = acc0 + acc1;
      // diag exchange, wave-private via bpermute (r8/r9-verified):
      // diag[d] lives in lane d+16*(d>>2), register acc[d&3].
      float mydiag = acc[0];
      mydiag = ((r & 3) == 1) ? acc[1] : mydiag;
      mydiag = ((r & 3) == 2) ? acc[2] : mydiag;
      mydiag = ((r & 3) == 3) ? acc[3] : mydiag;
      int md = __builtin_bit_cast(int, mydiag);
      float dcol = __builtin_bit_cast(float,
          __builtin_amdgcn_ds_bpermute(4*(r + 16*(r >> 2)), md));
      float sc = 0.f;
#pragma unroll
      for (int qq = 0; qq < 4; ++qq){
        float drow = __builtin_bit_cast(float,
            __builtin_amdgcn_ds_bpermute(4*(20*g + qq), md));
        int row = g*4 + qq;
        float sqd = drow + dcol - 2.f*acc[qq];
        float dist = sqrtf(fmaxf(sqd, 0.f));
        sc += (((row < 8) == (r < 8)) ? -dist : dist);
      }
      gene_acc += sc;
    }
    __syncthreads();                   // cellbuf half ready (only barrier per pass)
    if (h == 0) cell_accum<0>(cb, f, cacc);
    else        cell_accum<1>(cb, f, cacc);
    // no trailing barrier: pass p+2's writes to this half are ordered by
    // pass p+1's barrier (every thread consumed this half before reaching it)
  }
  // gene reduction: per-wave shuffle, one entry per wave
#pragma unroll
  for (int off = 32; off > 0; off >>= 1) gene_acc += __shfl_xor(gene_acc, off);
  if (lane == 0) gene_part[blockIdx.x*4 + wave] = gene_acc * (1.f/128.f);
  // cell partials in bf16 (coalesced across t)
  unsigned short* dst = cell_partials + (size_t)blockIdx.x * NOUT;
#pragma unroll
  for (int u = 0; u < NH; ++u){
    __hip_bfloat16 bv = __float2bfloat16(cacc[u]);   // RNE
    unsigned short sv; __builtin_memcpy(&sv, &bv, 2);
    dst[u*256 + t] = sv;
  }
}

__global__ __launch_bounds__(256) void reduce1_kernel(const unsigned short* __restrict__ partials,
                                                      float* __restrict__ partial2){
  int o = (blockIdx.x % 68)*256 + threadIdx.x;   // 68*256 = NOUT exactly
  int c = blockIdx.x / 68;                       // NCHUNK chunks of 64 blocks
  int p0 = c*64, p1 = p0 + 64;
  float s0=0.f, s1=0.f, s2=0.f, s3=0.f;
  for (int p = p0; p < p1; p += 4){
    s0 += bf2f(partials[(size_t)(p+0)*NOUT + o]);
    s1 += bf2f(partials[(size_t)(p+1)*NOUT + o]);
    s2 += bf2f(partials[(size_t)(p+2)*NOUT + o]);
    s3 += bf2f(partials[(size_t)(p+3)*NOUT + o]);
  }
  partial2[(size_t)c*NOUT + o] = (s0+s1)+(s2+s3);
}

__device__ inline float getGs(const float* Gs, int f, int i, int j){
  int a = i < j ? i : j, c = i < j ? j : i;
  int k = a*16 - (a*(a-1))/2 + (c - a);          // linear index of (a,c), a<=c
  int hh = (k >= NH) ? 1 : 0;
  int u = k - hh*NH;
  return Gs[u*256 + hh*128 + f];
}

// Merged reduce2 + final: G assembled in LDS, then both loss terms.
__global__ __launch_bounds__(256) void final_kernel(const float* __restrict__ partial2,
                                                    const float* __restrict__ gene_part,
                                                    int ngp, float* __restrict__ out){
  __shared__ float Gs[NOUT];           // 69.6 KB
  __shared__ float red[256];
  int t = threadIdx.x;
#pragma unroll
  for (int k = 0; k < NH; ++k){
    int o = k*256 + t;
    float s = 0.f;
#pragma unroll
    for (int c = 0; c < NCHUNK; ++c) s += partial2[(size_t)c*NOUT + o];
    Gs[o] = s;
  }
  __syncthreads();
  float v = 0.f;
  if (t < 128){
    int f = t;
    float d[16];
#pragma unroll
    for (int i = 0; i < 16; ++i) d[i] = getGs(Gs, f, i, i);
    float sum = 0.f;
#pragma unroll
    for (int i = 0; i < 16; ++i){
#pragma unroll
      for (int j = 0; j < 16; ++j){
        float sqd = d[i] + d[j] - 2.f*getGs(Gs, f, i, j);
        float dist = sqrtf(fmaxf(sqd, 0.f));
        sum += (((i < 8) == (j < 8)) ? -dist : dist);
      }
    }
    v = sum * (1.f/128.f) * (1.f/128.f);         // per-feature value / 128 features
  }
  float gp = 0.f;
  for (int idx = t; idx < ngp; idx += 256) gp += gene_part[idx];
  v += gp * (1.f/16384.f);                       // mean over clouds
  red[t] = v;
  __syncthreads();
  for (int s2 = 128; s2 > 0; s2 >>= 1){
    if (t < s2) red[t] += red[t + s2];
    __syncthreads();
  }
  if (t == 0) out[0] = red[0];
}

extern "C" void kernel_launch(void* const* d_in, const int* in_sizes, int n_in,
                              void* d_out, int out_size, void* d_ws, size_t ws_size,
                              hipStream_t stream){
  const float* X = (const float*)d_in[0];
  const float* Y = (const float*)d_in[1];
  float* out = (float*)d_out;

  float* wsf       = (float*)d_ws;
  float* gene_part = wsf;                            // NBLK*4 = 2048 floats
  float* partial2  = wsf + 2048;                     // NCHUNK*NOUT floats
  unsigned short* partials =
      (unsigned short*)(wsf + 2048 + NCHUNK*NOUT);   // NBLK*NOUT bf16 (~17.8 MB)

  fused_kernel<<<NBLK, 256, 0, stream>>>(X, Y, partials, gene_part);
  reduce1_kernel<<<68*NCHUNK, 256, 0, stream>>>(partials, partial2);
  final_kernel<<<1, 256, 0, stream>>>(partial2, gene_part, 4*NBLK, out);
}

// Round 11
// 130.896 us; speedup vs baseline: 1.1914x; 1.0157x over previous
//
#include <hip/hip_runtime.h>
#include <hip/hip_bf16.h>

#define NPAIR 136
#define NH 68          // pairs per half (136 = 2*68)
#define NOUT 17408     // NH * 256 threads
#define NBLK 512       // fused grid: 32 clouds/block
#define NCHUNK 8       // reduce1 chunks (NBLK/64)

using frag8 = __attribute__((ext_vector_type(8))) short;
using f32x4 = __attribute__((ext_vector_type(4))) float;
using i32x4 = __attribute__((ext_vector_type(4))) int;

// Pack two f32 -> bf16x2 by truncation with ONE v_perm_b32.
__device__ inline int pack_bf16(float lo, float hi){
  unsigned a, b;
  __builtin_memcpy(&a, &hi, 4);
  __builtin_memcpy(&b, &lo, 4);
  return (int)__builtin_amdgcn_perm(a, b, 0x07060302u);
}

__device__ inline float bf2f(unsigned short v){
  unsigned u32 = ((unsigned)v) << 16;
  float f; __builtin_memcpy(&f, &u32, 4);
  return f;
}

struct PairTab { int pi[NPAIR]; int pj[NPAIR]; };
constexpr PairTab make_pairs(){
  PairTab t{}; int u = 0;
  for (int i = 0; i < 16; ++i) for (int j = i; j < 16; ++j){ t.pi[u]=i; t.pj[u]=j; ++u; }
  return t;
}
constexpr PairTab PT = make_pairs();

// Consumer: accumulate 68 pair-products for feature f over 8 clouds in cb.
// cb layout: [cloud 0..7][row 0..15][f 0..127] bf16, byte ^= ((row&7)<<4) swizzle.
template<int H>
__device__ inline void cell_accum(const char* cb, int f, float (&cacc)[NH]){
#pragma unroll
  for (int c = 0; c < 8; ++c){
    float z[16];
#pragma unroll
    for (int rr = 0; rr < 16; ++rr){
      int byte = ((c*16 + rr)*256 + f*2) ^ ((rr & 7) << 4);
      unsigned short v = *reinterpret_cast<const unsigned short*>(cb + byte);
      z[rr] = bf2f(v);
    }
#pragma unroll
    for (int u = 0; u < NH; ++u)      // compile-time pair indices -> all regs
      cacc[u] = fmaf(z[PT.pi[H*NH+u]], z[PT.pj[H*NH+u]], cacc[u]);
  }
}

// ---- inline-asm streaming: compiler-invisible loads + hand-counted vmcnt ----
// Two dwordx4 per kk at byte offsets kk*128 and kk*128+16 from per-lane addr pp.
#define ISSUE(OFF0, OFF1, D0, D1) \
  asm volatile("global_load_dwordx4 %0, %2, off offset:" OFF0 "\n\t" \
               "global_load_dwordx4 %1, %2, off offset:" OFF1 \
               : "=&v"(D0), "=&v"(D1) : "v"(pp));

#define WAITC(N) \
  asm volatile("s_waitcnt vmcnt(" #N ")"); \
  __builtin_amdgcn_sched_barrier(0);

#define CONSUME(KK, D0, D1) { \
  i32x4 fi; \
  fi[0] = pack_bf16((D0).x, (D0).y); fi[1] = pack_bf16((D0).z, (D0).w); \
  fi[2] = pack_bf16((D1).x, (D1).y); fi[3] = pack_bf16((D1).z, (D1).w); \
  if ((KK) >= 12){ \
    int byte_ = ((ci*16 + r)*256 + ((KK)-12)*64 + g*16) ^ ((r & 7) << 4); \
    *reinterpret_cast<i32x4*>(cb + byte_) = fi; } \
  frag8 fr = __builtin_bit_cast(frag8, fi); \
  if ((KK) & 1) acc1 = __builtin_amdgcn_mfma_f32_16x16x32_bf16(fr, fr, acc1, 0, 0, 0); \
  else          acc0 = __builtin_amdgcn_mfma_f32_16x16x32_bf16(fr, fr, acc0, 0, 0, 0); }

// ---- fused: gene Gram via MFMA + cell Gram from the same loaded data ----
__global__ __launch_bounds__(256) void fused_kernel(const float* __restrict__ X,
                                                    const float* __restrict__ Y,
                                                    unsigned short* __restrict__ cell_partials,
                                                    float* __restrict__ gene_part){
  __shared__ char cellbuf[65536];      // 2 x (8 clouds x 16 rows x 128 f bf16)
  const int t = threadIdx.x;
  const int wave = t >> 6, lane = t & 63;
  const int r = lane & 15;             // row of Z (0-7 = X, 8-15 = Y)
  const int g = lane >> 4;             // k-group
  const int f = t & 127;               // cell feature
  const int h = t >> 7;                // pair-half 0/1 (wave-uniform)

  float cacc[NH];
#pragma unroll
  for (int u = 0; u < NH; ++u) cacc[u] = 0.f;
  float gene_acc = 0.f;

  const int cbase = blockIdx.x * 32;   // 32 clouds per block: 4 passes x 8 clouds
  for (int pass = 0; pass < 4; ++pass){
    char* cb = cellbuf + (pass & 1)*32768;
#pragma unroll
    for (int sub = 0; sub < 2; ++sub){
      const int ci = sub*4 + wave;                  // cloud slot 0..7 in this pass
      const int b = cbase + pass*8 + ci;
      const float* base = (r < 8) ? X + (size_t)b*4096 + (size_t)r*512
                                  : Y + (size_t)b*4096 + (size_t)(r-8)*512;
      const float* pp = base + g*8;                 // per-lane stream base
      f32x4 acc0 = {0.f,0.f,0.f,0.f}, acc1 = {0.f,0.f,0.f,0.f};
      float4 B0,B1,B2,B3,B4,B5,B6,B7,B8,B9,B10,B11,B12,B13,B14,B15;
      // prologue: 16 loads (kk 0..7) in flight
      ISSUE("0",   "16",  B0, B1)
      ISSUE("128", "144", B2, B3)
      ISSUE("256", "272", B4, B5)
      ISSUE("384", "400", B6, B7)
      ISSUE("512", "528", B8, B9)
      ISSUE("640", "656", B10,B11)
      ISSUE("768", "784", B12,B13)
      ISSUE("896", "912", B14,B15)
      // steady state: consume kk, reissue kk+8 into the freed pair
      WAITC(14) CONSUME(0, B0, B1)  ISSUE("1024","1040",B0, B1)
      WAITC(14) CONSUME(1, B2, B3)  ISSUE("1152","1168",B2, B3)
      WAITC(14) CONSUME(2, B4, B5)  ISSUE("1280","1296",B4, B5)
      WAITC(14) CONSUME(3, B6, B7)  ISSUE("1408","1424",B6, B7)
      WAITC(14) CONSUME(4, B8, B9)  ISSUE("1536","1552",B8, B9)
      WAITC(14) CONSUME(5, B10,B11) ISSUE("1664","1680",B10,B11)
      WAITC(14) CONSUME(6, B12,B13) ISSUE("1792","1808",B12,B13)
      WAITC(14) CONSUME(7, B14,B15) ISSUE("1920","1936",B14,B15)
      // drain
      WAITC(14) CONSUME(8,  B0, B1)
      WAITC(12) CONSUME(9,  B2, B3)
      WAITC(10) CONSUME(10, B4, B5)
      WAITC(8)  CONSUME(11, B6, B7)
      WAITC(6)  CONSUME(12, B8, B9)
      WAITC(4)  CONSUME(13, B10,B11)
      WAITC(2)  CONSUME(14, B12,B13)
      WAITC(0)  CONSUME(15, B14,B15)
      f32x4 acc = acc0 + acc1;
      // diag exchange, wave-private via bpermute (r8/r9-verified):
      // diag[d] lives in lane d+16*(d>>2), register acc[d&3].
      float mydiag = acc[0];
      mydiag = ((r & 3) == 1) ? acc[1] : mydiag;
      mydiag = ((r & 3) == 2) ? acc[2] : mydiag;
      mydiag = ((r & 3) == 3) ? acc[3] : mydiag;
      int md = __builtin_bit_cast(int, mydiag);
      float dcol = __builtin_bit_cast(float,
          __builtin_amdgcn_ds_bpermute(4*(r + 16*(r >> 2)), md));
      float sc = 0.f;
#pragma unroll
      for (int qq = 0; qq < 4; ++qq){
        float drow = __builtin_bit_cast(float,
            __builtin_amdgcn_ds_bpermute(4*(20*g + qq), md));
        int row = g*4 + qq;
        float sqd = drow + dcol - 2.f*acc[qq];
        float dist = sqrtf(fmaxf(sqd, 0.f));
        sc += (((row < 8) == (r < 8)) ? -dist : dist);
      }
      gene_acc += sc;
    }
    __syncthreads();                   // cellbuf half ready (only barrier per pass)
    if (h == 0) cell_accum<0>(cb, f, cacc);
    else        cell_accum<1>(cb, f, cacc);
    // no trailing barrier: pass p+2's writes to this half are ordered by
    // pass p+1's barrier (every thread consumed this half before reaching it)
  }
  // gene reduction: per-wave shuffle, one entry per wave
#pragma unroll
  for (int off = 32; off > 0; off >>= 1) gene_acc += __shfl_xor(gene_acc, off);
  if (lane == 0) gene_part[blockIdx.x*4 + wave] = gene_acc * (1.f/128.f);
  // cell partials in bf16 (coalesced across t)
  unsigned short* dst = cell_partials + (size_t)blockIdx.x * NOUT;
#pragma unroll
  for (int u = 0; u < NH; ++u){
    __hip_bfloat16 bv = __float2bfloat16(cacc[u]);   // RNE
    unsigned short sv; __builtin_memcpy(&sv, &bv, 2);
    dst[u*256 + t] = sv;
  }
}

__global__ __launch_bounds__(256) void reduce1_kernel(const unsigned short* __restrict__ partials,
                                                      float* __restrict__ partial2){
  int o = (blockIdx.x % 68)*256 + threadIdx.x;   // 68*256 = NOUT exactly
  int c = blockIdx.x / 68;                       // NCHUNK chunks of 64 blocks
  int p0 = c*64, p1 = p0 + 64;
  float s0=0.f, s1=0.f, s2=0.f, s3=0.f;
  for (int p = p0; p < p1; p += 4){
    s0 += bf2f(partials[(size_t)(p+0)*NOUT + o]);
    s1 += bf2f(partials[(size_t)(p+1)*NOUT + o]);
    s2 += bf2f(partials[(size_t)(p+2)*NOUT + o]);
    s3 += bf2f(partials[(size_t)(p+3)*NOUT + o]);
  }
  partial2[(size_t)c*NOUT + o] = (s0+s1)+(s2+s3);
}

__device__ inline float getGs(const float* Gs, int f, int i, int j){
  int a = i < j ? i : j, c = i < j ? j : i;
  int k = a*16 - (a*(a-1))/2 + (c - a);          // linear index of (a,c), a<=c
  int hh = (k >= NH) ? 1 : 0;
  int u = k - hh*NH;
  return Gs[u*256 + hh*128 + f];
}

// Merged reduce2 + final: G assembled in LDS, then both loss terms.
__global__ __launch_bounds__(256) void final_kernel(const float* __restrict__ partial2,
                                                    const float* __restrict__ gene_part,
                                                    int ngp, float* __restrict__ out){
  __shared__ float Gs[NOUT];           // 69.6 KB
  __shared__ float red[256];
  int t = threadIdx.x;
#pragma unroll
  for (int k = 0; k < NH; ++k){
    int o = k*256 + t;
    float s = 0.f;
#pragma unroll
    for (int c = 0; c < NCHUNK; ++c) s += partial2[(size_t)c*NOUT + o];
    Gs[o] = s;
  }
  __syncthreads();
  float v = 0.f;
  if (t < 128){
    int f = t;
    float d[16];
#pragma unroll
    for (int i = 0; i < 16; ++i) d[i] = getGs(Gs, f, i, i);
    float sum = 0.f;
#pragma unroll
    for (int i = 0; i < 16; ++i){
#pragma unroll
      for (int j = 0; j < 16; ++j){
        float sqd = d[i] + d[j] - 2.f*getGs(Gs, f, i, j);
        float dist = sqrtf(fmaxf(sqd, 0.f));
        sum += (((i < 8) == (j < 8)) ? -dist : dist);
      }
    }
    v = sum * (1.f/128.f) * (1.f/128.f);         // per-feature value / 128 features
  }
  float gp = 0.f;
  for (int idx = t; idx < ngp; idx += 256) gp += gene_part[idx];
  v += gp * (1.f/16384.f);                       // mean over clouds
  red[t] = v;
  __syncthreads();
  for (int s2 = 128; s2 > 0; s2 >>= 1){
    if (t < s2) red[t] += red[t + s2];
    __syncthreads();
  }
  if (t == 0) out[0] = red[0];
}

extern "C" void kernel_launch(void* const* d_in, const int* in_sizes, int n_in,
                              void* d_out, int out_size, void* d_ws, size_t ws_size,
                              hipStream_t stream){
  const float* X = (const float*)d_in[0];
  const float* Y = (const float*)d_in[1];
  float* out = (float*)d_out;

  float* wsf       = (float*)d_ws;
  float* gene_part = wsf;                            // NBLK*4 = 2048 floats
  float* partial2  = wsf + 2048;                     // NCHUNK*NOUT floats
  unsigned short* partials =
      (unsigned short*)(wsf + 2048 + NCHUNK*NOUT);   // NBLK*NOUT bf16 (~17.8 MB)

  fused_kernel<<<NBLK, 256, 0, stream>>>(X, Y, partials, gene_part);
  reduce1_kernel<<<68*NCHUNK, 256, 0, stream>>>(partials, partial2);
  final_kernel<<<1, 256, 0, stream>>>(partial2, gene_part, 4*NBLK, out);
}

// Round 12
// 126.403 us; speedup vs baseline: 1.2338x; 1.0355x over previous
//
#include <hip/hip_runtime.h>
#include <hip/hip_bf16.h>

#define NPAIR 136
#define NH 68          // pairs per half (136 = 2*68)
#define NOUT 17408     // NH * 256 threads
#define NBLK 512       // fused grid: 32 clouds/block
#define NCHUNK 8       // reduce1 chunks (NBLK/64)

using frag8 = __attribute__((ext_vector_type(8))) short;
using f32x4 = __attribute__((ext_vector_type(4))) float;
using i32x4 = __attribute__((ext_vector_type(4))) int;

// Pack two f32 -> bf16x2 by truncation with ONE v_perm_b32.
__device__ inline int pack_bf16(float lo, float hi){
  unsigned a, b;
  __builtin_memcpy(&a, &hi, 4);
  __builtin_memcpy(&b, &lo, 4);
  return (int)__builtin_amdgcn_perm(a, b, 0x07060302u);
}

__device__ inline float bf2f(unsigned short v){
  unsigned u32 = ((unsigned)v) << 16;
  float f; __builtin_memcpy(&f, &u32, 4);
  return f;
}

struct PairTab { int pi[NPAIR]; int pj[NPAIR]; };
constexpr PairTab make_pairs(){
  PairTab t{}; int u = 0;
  for (int i = 0; i < 16; ++i) for (int j = i; j < 16; ++j){ t.pi[u]=i; t.pj[u]=j; ++u; }
  return t;
}
constexpr PairTab PT = make_pairs();

// Consumer: accumulate 68 pair-products for feature f over 8 clouds in cb.
// cb layout: [cloud 0..7][row 0..15][f 0..127] bf16, byte ^= ((row&7)<<4) swizzle.
template<int H>
__device__ inline void cell_accum(const char* cb, int f, float (&cacc)[NH]){
#pragma unroll
  for (int c = 0; c < 8; ++c){
    float z[16];
#pragma unroll
    for (int rr = 0; rr < 16; ++rr){
      int byte = ((c*16 + rr)*256 + f*2) ^ ((rr & 7) << 4);
      unsigned short v = *reinterpret_cast<const unsigned short*>(cb + byte);
      z[rr] = bf2f(v);
    }
#pragma unroll
    for (int u = 0; u < NH; ++u)      // compile-time pair indices -> all regs
      cacc[u] = fmaf(z[PT.pi[H*NH+u]], z[PT.pj[H*NH+u]], cacc[u]);
  }
}

// ---- inline-asm streaming: compiler-invisible loads + hand-counted vmcnt ----
// Two dwordx4 per kk at byte offsets kk*128 and kk*128+16 from per-lane addr pp.
#define ISSUE(OFF0, OFF1, D0, D1) \
  asm volatile("global_load_dwordx4 %0, %2, off offset:" OFF0 "\n\t" \
               "global_load_dwordx4 %1, %2, off offset:" OFF1 \
               : "=&v"(D0), "=&v"(D1) : "v"(pp));

#define WAITC(N) \
  asm volatile("s_waitcnt vmcnt(" #N ")"); \
  __builtin_amdgcn_sched_barrier(0);

#define CONSUME(KK, D0, D1) { \
  i32x4 fi; \
  fi[0] = pack_bf16((D0).x, (D0).y); fi[1] = pack_bf16((D0).z, (D0).w); \
  fi[2] = pack_bf16((D1).x, (D1).y); fi[3] = pack_bf16((D1).z, (D1).w); \
  if ((KK) >= 12){ \
    int byte_ = ((ci*16 + r)*256 + ((KK)-12)*64 + g*16) ^ ((r & 7) << 4); \
    *reinterpret_cast<i32x4*>(cb + byte_) = fi; } \
  frag8 fr = __builtin_bit_cast(frag8, fi); \
  if ((KK) & 1) acc1 = __builtin_amdgcn_mfma_f32_16x16x32_bf16(fr, fr, acc1, 0, 0, 0); \
  else          acc0 = __builtin_amdgcn_mfma_f32_16x16x32_bf16(fr, fr, acc0, 0, 0, 0); }

// ---- fused: gene Gram via MFMA + cell Gram from the same loaded data ----
__global__ __launch_bounds__(256) void fused_kernel(const float* __restrict__ X,
                                                    const float* __restrict__ Y,
                                                    unsigned short* __restrict__ cell_partials,
                                                    float* __restrict__ gene_part){
  __shared__ char cellbuf[65536];      // 2 x (8 clouds x 16 rows x 128 f bf16)
  const int t = threadIdx.x;
  const int wave = t >> 6, lane = t & 63;
  const int r = lane & 15;             // row of Z (0-7 = X, 8-15 = Y)
  const int g = lane >> 4;             // k-group
  const int f = t & 127;               // cell feature
  const int h = t >> 7;                // pair-half 0/1 (wave-uniform)

  float cacc[NH];
#pragma unroll
  for (int u = 0; u < NH; ++u) cacc[u] = 0.f;
  float gene_acc = 0.f;

  const int cbase = blockIdx.x * 32;   // 32 clouds per block: 4 passes x 8 clouds
  for (int pass = 0; pass < 4; ++pass){
    char* cb = cellbuf + (pass & 1)*32768;
#pragma unroll
    for (int sub = 0; sub < 2; ++sub){
      const int ci = sub*4 + wave;                  // cloud slot 0..7 in this pass
      const int b = cbase + pass*8 + ci;
      const float* base = (r < 8) ? X + (size_t)b*4096 + (size_t)r*512
                                  : Y + (size_t)b*4096 + (size_t)(r-8)*512;
      const float* pp = base + g*8;                 // per-lane stream base
      f32x4 acc0 = {0.f,0.f,0.f,0.f}, acc1 = {0.f,0.f,0.f,0.f};
      float4 B0,B1,B2,B3,B4,B5,B6,B7,B8,B9,B10,B11,B12,B13,B14,B15;
      // prologue: 16 loads (kk 0..7) in flight
      ISSUE("0",   "16",  B0, B1)
      ISSUE("128", "144", B2, B3)
      ISSUE("256", "272", B4, B5)
      ISSUE("384", "400", B6, B7)
      ISSUE("512", "528", B8, B9)
      ISSUE("640", "656", B10,B11)
      ISSUE("768", "784", B12,B13)
      ISSUE("896", "912", B14,B15)
      // steady state: consume kk, reissue kk+8 into the freed pair
      WAITC(14) CONSUME(0, B0, B1)  ISSUE("1024","1040",B0, B1)
      WAITC(14) CONSUME(1, B2, B3)  ISSUE("1152","1168",B2, B3)
      WAITC(14) CONSUME(2, B4, B5)  ISSUE("1280","1296",B4, B5)
      WAITC(14) CONSUME(3, B6, B7)  ISSUE("1408","1424",B6, B7)
      WAITC(14) CONSUME(4, B8, B9)  ISSUE("1536","1552",B8, B9)
      WAITC(14) CONSUME(5, B10,B11) ISSUE("1664","1680",B10,B11)
      WAITC(14) CONSUME(6, B12,B13) ISSUE("1792","1808",B12,B13)
      WAITC(14) CONSUME(7, B14,B15) ISSUE("1920","1936",B14,B15)
      // drain
      WAITC(14) CONSUME(8,  B0, B1)
      WAITC(12) CONSUME(9,  B2, B3)
      WAITC(10) CONSUME(10, B4, B5)
      WAITC(8)  CONSUME(11, B6, B7)
      WAITC(6)  CONSUME(12, B8, B9)
      WAITC(4)  CONSUME(13, B10,B11)
      WAITC(2)  CONSUME(14, B12,B13)
      WAITC(0)  CONSUME(15, B14,B15)
      f32x4 acc = acc0 + acc1;
      // diag exchange, wave-private via bpermute (r8/r9-verified):
      // diag[d] lives in lane d+16*(d>>2), register acc[d&3].
      float mydiag = acc[0];
      mydiag = ((r & 3) == 1) ? acc[1] : mydiag;
      mydiag = ((r & 3) == 2) ? acc[2] : mydiag;
      mydiag = ((r & 3) == 3) ? acc[3] : mydiag;
      int md = __builtin_bit_cast(int, mydiag);
      float dcol = __builtin_bit_cast(float,
          __builtin_amdgcn_ds_bpermute(4*(r + 16*(r >> 2)), md));
      float sc = 0.f;
#pragma unroll
      for (int qq = 0; qq < 4; ++qq){
        float drow = __builtin_bit_cast(float,
            __builtin_amdgcn_ds_bpermute(4*(20*g + qq), md));
        int row = g*4 + qq;
        float sqd = drow + dcol - 2.f*acc[qq];
        float dist = sqrtf(fmaxf(sqd, 0.f));
        sc += (((row < 8) == (r < 8)) ? -dist : dist);
      }
      gene_acc += sc;
    }
    __syncthreads();                   // cellbuf half ready (only barrier per pass)
    if (h == 0) cell_accum<0>(cb, f, cacc);
    else        cell_accum<1>(cb, f, cacc);
    // no trailing barrier: pass p+2's writes to this half are ordered by
    // pass p+1's barrier (every thread consumed this half before reaching it)
  }
  // gene reduction: per-wave shuffle, one entry per wave
#pragma unroll
  for (int off = 32; off > 0; off >>= 1) gene_acc += __shfl_xor(gene_acc, off);
  if (lane == 0) gene_part[blockIdx.x*4 + wave] = gene_acc * (1.f/128.f);
  // cell partials in bf16 (coalesced across t)
  unsigned short* dst = cell_partials + (size_t)blockIdx.x * NOUT;
#pragma unroll
  for (int u = 0; u < NH; ++u){
    __hip_bfloat16 bv = __float2bfloat16(cacc[u]);   // RNE
    unsigned short sv; __builtin_memcpy(&sv, &bv, 2);
    dst[u*256 + t] = sv;
  }
}

__global__ __launch_bounds__(256) void reduce1_kernel(const unsigned short* __restrict__ partials,
                                                      float* __restrict__ partial2){
  int o = (blockIdx.x % 68)*256 + threadIdx.x;   // 68*256 = NOUT exactly
  int c = blockIdx.x / 68;                       // NCHUNK chunks of 64 blocks
  int p0 = c*64, p1 = p0 + 64;
  float s0=0.f, s1=0.f, s2=0.f, s3=0.f;
  for (int p = p0; p < p1; p += 4){
    s0 += bf2f(partials[(size_t)(p+0)*NOUT + o]);
    s1 += bf2f(partials[(size_t)(p+1)*NOUT + o]);
    s2 += bf2f(partials[(size_t)(p+2)*NOUT + o]);
    s3 += bf2f(partials[(size_t)(p+3)*NOUT + o]);
  }
  partial2[(size_t)c*NOUT + o] = (s0+s1)+(s2+s3);
}

// Parallel 557KB -> 68KB reduction (68 blocks); removes the single-block
// serial global read that final_kernel was paying (~15-18us on one CU).
__global__ __launch_bounds__(256) void reduce2_kernel(const float* __restrict__ partial2,
                                                      float* __restrict__ G){
  int o = blockIdx.x*256 + threadIdx.x;          // grid 68
  float s = 0.f;
#pragma unroll
  for (int c = 0; c < NCHUNK; ++c) s += partial2[(size_t)c*NOUT + o];
  G[o] = s;
}

__device__ inline float getGs(const float* Gs, int f, int i, int j){
  int a = i < j ? i : j, c = i < j ? j : i;
  int k = a*16 - (a*(a-1))/2 + (c - a);          // linear index of (a,c), a<=c
  int hh = (k >= NH) ? 1 : 0;
  int u = k - hh*NH;
  return Gs[u*256 + hh*128 + f];
}

__global__ __launch_bounds__(256) void final_kernel(const float* __restrict__ G,
                                                    const float* __restrict__ gene_part,
                                                    int ngp, float* __restrict__ out){
  __shared__ float Gs[NOUT];           // 69.6 KB, loaded from 68KB Gbuf
  __shared__ float red[256];
  int t = threadIdx.x;
#pragma unroll
  for (int k = 0; k < NH; ++k) Gs[k*256 + t] = G[k*256 + t];
  __syncthreads();
  float v = 0.f;
  if (t < 128){
    int f = t;
    float d[16];
#pragma unroll
    for (int i = 0; i < 16; ++i) d[i] = getGs(Gs, f, i, i);
    float sum = 0.f;
#pragma unroll
    for (int i = 0; i < 16; ++i){
#pragma unroll
      for (int j = 0; j < 16; ++j){
        float sqd = d[i] + d[j] - 2.f*getGs(Gs, f, i, j);
        float dist = sqrtf(fmaxf(sqd, 0.f));
        sum += (((i < 8) == (j < 8)) ? -dist : dist);
      }
    }
    v = sum * (1.f/128.f) * (1.f/128.f);         // per-feature value / 128 features
  }
  float gp = 0.f;
  for (int idx = t; idx < ngp; idx += 256) gp += gene_part[idx];
  v += gp * (1.f/16384.f);                       // mean over clouds
  red[t] = v;
  __syncthreads();
  for (int s2 = 128; s2 > 0; s2 >>= 1){
    if (t < s2) red[t] += red[t + s2];
    __syncthreads();
  }
  if (t == 0) out[0] = red[0];
}

extern "C" void kernel_launch(void* const* d_in, const int* in_sizes, int n_in,
                              void* d_out, int out_size, void* d_ws, size_t ws_size,
                              hipStream_t stream){
  const float* X = (const float*)d_in[0];
  const float* Y = (const float*)d_in[1];
  float* out = (float*)d_out;

  float* wsf       = (float*)d_ws;
  float* gene_part = wsf;                            // NBLK*4 = 2048 floats
  float* Gbuf      = wsf + 2048;                     // NOUT floats
  float* partial2  = wsf + 2048 + NOUT;              // NCHUNK*NOUT floats
  unsigned short* partials =
      (unsigned short*)(wsf + 2048 + (1+NCHUNK)*NOUT);  // NBLK*NOUT bf16 (~17.8 MB)

  fused_kernel<<<NBLK, 256, 0, stream>>>(X, Y, partials, gene_part);
  reduce1_kernel<<<68*NCHUNK, 256, 0, stream>>>(partials, partial2);
  reduce2_kernel<<<68, 256, 0, stream>>>(partial2, Gbuf);
  final_kernel<<<1, 256, 0, stream>>>(Gbuf, gene_part, 4*NBLK, out);
}